// Round 10
// baseline (243.443 us; speedup 1.0000x reference)
//
#include <hip/hip_runtime.h>
#include <stdint.h>

#define SEQ 2048
#define MROWS 8192
#define LOG2E 1.44269504f

typedef __attribute__((ext_vector_type(8))) _Float16 f16x8;
typedef __attribute__((ext_vector_type(4))) _Float16 f16x4;
typedef __attribute__((ext_vector_type(2))) __fp16 fp16x2_t;   // cvt_pkrtz return type
typedef __attribute__((ext_vector_type(8))) unsigned short ushort8;
typedef __attribute__((ext_vector_type(4))) unsigned short ushort4_t;
typedef __attribute__((ext_vector_type(4))) float f32x4;

__device__ __forceinline__ unsigned short f32_to_f16u(float f) {
  union { _Float16 h; unsigned short u; } v; v.h = (_Float16)f; return v.u;
}

__device__ __forceinline__ ushort8 pack8_rtz(float4 f0, float4 f1) {
  union { fp16x2_t h2[4]; ushort8 u8; } pk;
  pk.h2[0] = __builtin_amdgcn_cvt_pkrtz(f0.x, f0.y);
  pk.h2[1] = __builtin_amdgcn_cvt_pkrtz(f0.z, f0.w);
  pk.h2[2] = __builtin_amdgcn_cvt_pkrtz(f1.x, f1.y);
  pk.h2[3] = __builtin_amdgcn_cvt_pkrtz(f1.z, f1.w);
  return pk.u8;
}

// async global(16B/lane) -> LDS (wave-uniform base + lane*16)
__device__ __forceinline__ void gload16(const void* g, void* l) {
  __builtin_amdgcn_global_load_lds(
      (const __attribute__((address_space(1))) unsigned int*)g,
      (__attribute__((address_space(3))) unsigned int*)l, 16, 0, 0);
}

// ---------------- W f32 -> f16 conversion (4 planes of 1024x1024) ----------
__global__ __launch_bounds__(256) void wconv_k(
    const float* __restrict__ Wq, const float* __restrict__ Wk,
    const float* __restrict__ Wv, const float* __restrict__ Wo,
    unsigned short* __restrict__ WF)
{
  const int plane = blockIdx.y;
  const float* __restrict__ s = (plane==0)? Wq : (plane==1)? Wk : (plane==2)? Wv : Wo;
  size_t off = ((size_t)blockIdx.x*256 + threadIdx.x) * 8;
  float4 f0 = *(const float4*)(s + off);
  float4 f1 = *(const float4*)(s + off + 4);
  *(ushort8*)&WF[(size_t)plane*1048576 + off] = pack8_rtz(f0, f1);
}

// ---------------- fused QKV projection GEMM ----------------
// z=0: Q -> f16 plane (scaled by log2e); z=1: K; z=2: V -> per-head transposed
// A (f32) staged manually with cvt_pkrtz; B (f16 plane) via global_load_lds.
__global__ __launch_bounds__(256) void qkv_k(
    const float* __restrict__ Aq, const float* __restrict__ Ak, const float* __restrict__ Av,
    const unsigned short* __restrict__ WF,
    const float* __restrict__ bq, const float* __restrict__ bk, const float* __restrict__ bv,
    unsigned short* __restrict__ Qf, unsigned short* __restrict__ Kf, unsigned short* __restrict__ Vt)
{
  const int z = blockIdx.z;
  const float* __restrict__ A    = (z==0)? Aq : (z==1)? Ak : Av;
  const unsigned short* __restrict__ W = WF + (size_t)z*1048576;
  const float* __restrict__ bias = (z==0)? bq : (z==1)? bk : bv;

  __shared__ unsigned short Ah[128*32];
  __shared__ unsigned short Bh[128*32];

  const int tid  = threadIdx.x;
  const int lane = tid & 63;
  const int w    = tid >> 6;
  const int wm   = w >> 1, wn = w & 1;
  const int row0 = blockIdx.x * 128;
  const int col0 = blockIdx.y * 128;

  f32x4 acc[4][4] = {};

  for (int k0 = 0; k0 < 1024; k0 += 32) {
    __syncthreads();
    // ---- B tile via global_load_lds (pre-swizzled source, linear dest) ----
    #pragma unroll
    for (int j=0;j<2;++j) {
      int r  = w*32 + j*16 + (lane>>2);
      int sl = (lane & 3) ^ ((r>>1)&3);
      gload16(W + (size_t)(col0 + r)*1024 + k0 + sl*8, &Bh[(w*32 + j*16)*32]);
    }
    // ---- A tile manual (f32 -> f16 cvt_pkrtz) ----
    #pragma unroll
    for (int i = 0; i < 2; ++i) {
      int c = tid + i*256;            // 0..511 chunks of 8 elements
      int r = c >> 2, slot = c & 3;   // 128 rows x 4 slots
      int lidx = r*32 + ((slot ^ ((r >> 1) & 3))*8);
      const float* ap = A + (size_t)(row0 + r)*1024 + k0 + slot*8;
      float4 f0 = *(const float4*)ap;
      float4 f1 = *(const float4*)(ap + 4);
      *(ushort8*)&Ah[lidx] = pack8_rtz(f0, f1);
    }
    __syncthreads();

    f16x8 a_[4], b_[4];
    const int slotR = lane >> 4;
    #pragma unroll
    for (int m=0;m<4;++m) {
      int r = wm*64 + m*16 + (lane & 15);
      a_[m] = *(const f16x8*)&Ah[r*32 + ((slotR ^ ((r>>1)&3))*8)];
    }
    #pragma unroll
    for (int nn=0;nn<4;++nn) {
      int r = wn*64 + nn*16 + (lane & 15);
      b_[nn] = *(const f16x8*)&Bh[r*32 + ((slotR ^ ((r>>1)&3))*8)];
    }
    #pragma unroll
    for (int m=0;m<4;++m)
      #pragma unroll
      for (int nn=0;nn<4;++nn)
        acc[m][nn] = __builtin_amdgcn_mfma_f32_16x16x32_f16(a_[m], b_[nn], acc[m][nn],0,0,0);
  }

  // epilogue (C frag: col=lane&15, row=(lane>>4)*4+r)
  #pragma unroll
  for (int m=0;m<4;++m) {
    #pragma unroll
    for (int nn=0;nn<4;++nn) {
      int gcol = col0 + wn*64 + nn*16 + (lane & 15);
      float bsv = bias[gcol];
      if (z == 2) {
        int rbase = row0 + wm*64 + m*16 + (lane>>4)*4;
        int nIdx = rbase >> 11, s0 = rbase & 2047;
        ushort4_t pk;
        #pragma unroll
        for (int r2=0;r2<4;++r2) pk[r2] = f32_to_f16u(acc[m][nn][r2] + bsv);
        *(ushort4_t*)&Vt[((size_t)(nIdx*1024 + gcol))*2048 + s0] = pk;
      } else {
        unsigned short* __restrict__ dst = (z==0)? Qf : Kf;
        const float qsc = (z==0)? LOG2E : 1.0f;   // fold log2(e) into Q
        #pragma unroll
        for (int r2=0;r2<4;++r2) {
          int grow = row0 + wm*64 + m*16 + (lane>>4)*4 + r2;
          dst[(size_t)grow*1024 + gcol] = f32_to_f16u((acc[m][nn][r2] + bsv) * qsc);
        }
      }
    }
  }
}

// ---------------- output projection: out = AO(f16) @ WoF^T + bo (f32) ------
// BOTH operands staged via global_load_lds.
__global__ __launch_bounds__(256) void oproj_k(
    const unsigned short* __restrict__ AO, const unsigned short* __restrict__ W,
    const float* __restrict__ bias, float* __restrict__ out)
{
  __shared__ unsigned short Ah[128*32];
  __shared__ unsigned short Bh[128*32];

  const int tid  = threadIdx.x;
  const int lane = tid & 63;
  const int w    = tid >> 6;
  const int wm   = w >> 1, wn = w & 1;
  const int row0 = blockIdx.x * 128;
  const int col0 = blockIdx.y * 128;

  f32x4 acc[4][4] = {};

  for (int k0 = 0; k0 < 1024; k0 += 32) {
    __syncthreads();
    #pragma unroll
    for (int j=0;j<2;++j) {
      int r  = w*32 + j*16 + (lane>>2);
      int sl = (lane & 3) ^ ((r>>1)&3);
      gload16(AO + (size_t)(row0 + r)*1024 + k0 + sl*8, &Ah[(w*32 + j*16)*32]);
      gload16(W  + (size_t)(col0 + r)*1024 + k0 + sl*8, &Bh[(w*32 + j*16)*32]);
    }
    __syncthreads();

    f16x8 a_[4], b_[4];
    const int slotR = lane >> 4;
    #pragma unroll
    for (int m=0;m<4;++m) {
      int r = wm*64 + m*16 + (lane & 15);
      a_[m] = *(const f16x8*)&Ah[r*32 + ((slotR ^ ((r>>1)&3))*8)];
    }
    #pragma unroll
    for (int nn=0;nn<4;++nn) {
      int r = wn*64 + nn*16 + (lane & 15);
      b_[nn] = *(const f16x8*)&Bh[r*32 + ((slotR ^ ((r>>1)&3))*8)];
    }
    #pragma unroll
    for (int m=0;m<4;++m)
      #pragma unroll
      for (int nn=0;nn<4;++nn)
        acc[m][nn] = __builtin_amdgcn_mfma_f32_16x16x32_f16(a_[m], b_[nn], acc[m][nn],0,0,0);
  }

  #pragma unroll
  for (int m=0;m<4;++m)
    #pragma unroll
    for (int nn=0;nn<4;++nn) {
      int gcol = col0 + wn*64 + nn*16 + (lane & 15);
      float bsv = bias[gcol];
      #pragma unroll
      for (int r2=0;r2<4;++r2) {
        int grow = row0 + wm*64 + m*16 + (lane>>4)*4 + r2;
        out[(size_t)grow*1024 + gcol] = acc[m][nn][r2] + bsv;
      }
    }
}

// ---------------- Flash attention: register-P PV, latency-aware schedules --
// grid 1024 blocks (16 q-tiles of 128 x 64 heads), XCD-swizzled.
// 4 waves x 32 q-rows (qm=0,1); KVBLK=64, K/V double-buffered via
// global_load_lds (pre-swizzled source), 1 barrier/iter. LDS = 32 KB.
// QK^T: ks-outer schedule -> 8 independent MFMAs between s[] accumulator
// reuses. PV (16x16x16, P from registers): nf-outer schedule -> 8
// independent MFMAs between o[] accumulator reuses.
__global__ __launch_bounds__(256) void attn_k(
  const unsigned short* __restrict__ Qf, const unsigned short* __restrict__ Kf,
  const unsigned short* __restrict__ Vt, unsigned short* __restrict__ AO)
{
  __shared__ unsigned short Ks[2][64*64];   // K tile (swizzled)      16 KB
  __shared__ unsigned short Vs[2][64*64];   // V^T tile (swizzled)    16 KB

  const int tid = threadIdx.x, lane = tid & 63, w = tid >> 6;
  const int q = lane & 15, g = lane >> 4;

  // T1 XCD swizzle (bijective: 1024 % 8 == 0)
  const int bid = blockIdx.x;
  const int swz = (bid & 7) * 128 + (bid >> 3);
  const int qt = swz & 15, nh = swz >> 4;
  const int n = nh >> 4, h = nh & 15;

  // Q fragments (pre-scaled by log2e), 2 q-subtiles of 16 rows
  f16x8 qf[2][2];
  #pragma unroll
  for (int qm=0; qm<2; ++qm) {
    int qrow = n*SEQ + qt*128 + w*32 + qm*16 + q;
    #pragma unroll
    for (int ks=0; ks<2; ++ks)
      qf[qm][ks] = *(const f16x8*)&Qf[(size_t)qrow*1024 + h*64 + ks*32 + g*8];
  }

  f32x4 o[2][4] = {};       // O^T frags: o[qm][df][r] = O[q][d=df*16+4g+r]
  float mrun[2] = {-1e30f,-1e30f}, lrun[2] = {0.f,0.f};  // lrun = LANE-partial

  const size_t kbase = (size_t)(n*SEQ)*1024 + h*64;   // K plane [s][1024]
  const size_t vbase = ((size_t)(n*1024 + h*64))*SEQ; // Vt [d][s]

  // staging geometry: per gload16 a wave covers 8 rows x 128B;
  // source pre-swizzled (granule sl^(r&7)), LDS dest linear (rule #21)
  const int srow = lane >> 3;              // 0..7 row within 8-row group
  const int ssl  = (lane & 7) ^ srow;      // pre-swizzled 16B granule

  // prologue: stage K/V tile 0
  #pragma unroll
  for (int j=0;j<2;++j) {
    int r = w*16 + j*8 + srow;
    gload16(&Kf[kbase + (size_t)r*1024 + ssl*8], &Ks[0][(w*16+j*8)*64]);
    gload16(&Vt[vbase + (size_t)r*SEQ  + ssl*8], &Vs[0][(w*16+j*8)*64]);
  }
  __syncthreads();

  int cur = 0;
  for (int kt = 0; kt < 32; ++kt) {
    // ---- issue next tile's staging immediately (drains at the barrier) ----
    if (kt < 31) {
      #pragma unroll
      for (int j=0;j<2;++j) {
        int r = w*16 + j*8 + srow;
        gload16(&Kf[kbase + (size_t)((kt+1)*64 + r)*1024 + ssl*8], &Ks[cur^1][(w*16+j*8)*64]);
        gload16(&Vt[vbase + (size_t)r*SEQ + (kt+1)*64 + ssl*8],    &Vs[cur^1][(w*16+j*8)*64]);
      }
    }

    // ---- S^T = K * Q^T, ks-outer (8 independent MFMAs per chain step) ----
    f32x4 s[2][4];
    #pragma unroll
    for (int qm=0;qm<2;++qm)
      #pragma unroll
      for (int nf=0; nf<4; ++nf) s[qm][nf] = f32x4{0.f,0.f,0.f,0.f};
    #pragma unroll
    for (int ks=0; ks<2; ++ks) {
      f16x8 kb[4];
      #pragma unroll
      for (int nf=0; nf<4; ++nf)
        kb[nf] = *(const f16x8*)&Ks[cur][(nf*16+q)*64 + (((ks*4+g)^(q&7))*8)];
      __builtin_amdgcn_s_setprio(1);
      #pragma unroll
      for (int nf=0; nf<4; ++nf) {
        s[0][nf] = __builtin_amdgcn_mfma_f32_16x16x32_f16(kb[nf], qf[0][ks], s[0][nf],0,0,0);
        s[1][nf] = __builtin_amdgcn_mfma_f32_16x16x32_f16(kb[nf], qf[1][ks], s[1][nf],0,0,0);
      }
      __builtin_amdgcn_s_setprio(0);
    }

    // ---- softmax per q-subtile (defer-max) -> P fragments in REGISTERS ----
    f16x4 pfrag[2][4];        // pfrag[qm][nf] = P[nf*16+4g+{0..3}][q] as f16
    #pragma unroll
    for (int qm=0; qm<2; ++qm) {
      float ml = fmaxf(fmaxf(fmaxf(s[qm][0][0],s[qm][0][1]),fmaxf(s[qm][0][2],s[qm][0][3])),
                       fmaxf(fmaxf(s[qm][1][0],s[qm][1][1]),fmaxf(s[qm][1][2],s[qm][1][3])));
      float mh = fmaxf(fmaxf(fmaxf(s[qm][2][0],s[qm][2][1]),fmaxf(s[qm][2][2],s[qm][2][3])),
                       fmaxf(fmaxf(s[qm][3][0],s[qm][3][1]),fmaxf(s[qm][3][2],s[qm][3][3])));
      ml = fmaxf(ml, mh);
      if (!__all(ml <= mrun[qm] + 7.0f)) {
        // slow path: grow running max, rescale O and lane-partial lsum
        float m1 = fmaxf(ml, __shfl_xor(ml, 16, 64));
        float m2 = fmaxf(m1, __shfl_xor(m1, 32, 64));
        float mn = fmaxf(mrun[qm], m2);
        float sc = __builtin_amdgcn_exp2f(mrun[qm] - mn);
        lrun[qm] *= sc;
        mrun[qm] = mn;
        #pragma unroll
        for (int df=0; df<4; ++df)
          #pragma unroll
          for (int r=0;r<4;++r) o[qm][df][r] *= sc;
      }
      float m0 = mrun[qm];
      float rsl = 0.f;
      #pragma unroll
      for (int nf=0; nf<4; ++nf) {
        float p0 = __builtin_amdgcn_exp2f(s[qm][nf][0] - m0);
        float p1 = __builtin_amdgcn_exp2f(s[qm][nf][1] - m0);
        float p2 = __builtin_amdgcn_exp2f(s[qm][nf][2] - m0);
        float p3 = __builtin_amdgcn_exp2f(s[qm][nf][3] - m0);
        rsl += (p0 + p1) + (p2 + p3);
        union { fp16x2_t h2[2]; f16x4 h4; } pk;
        pk.h2[0] = __builtin_amdgcn_cvt_pkrtz(p0, p1);
        pk.h2[1] = __builtin_amdgcn_cvt_pkrtz(p2, p3);
        pfrag[qm][nf] = pk.h4;
      }
      lrun[qm] += rsl;          // lane-partial; cross-lane reduce at epilogue
    }

    // ---- O^T += V^T * P, nf-outer (8 independent MFMAs per chain step) ----
    #pragma unroll
    for (int nf=0; nf<4; ++nf) {
      f16x4 va[4];
      #pragma unroll
      for (int df=0; df<4; ++df) {
        int row = df*16 + q;
        int gran = 2*nf + (g>>1);
        va[df] = *(const f16x4*)&Vs[cur][row*64 + ((gran ^ (q&7))*8) + (g&1)*4];
      }
      __builtin_amdgcn_s_setprio(1);
      #pragma unroll
      for (int df=0; df<4; ++df) {
        o[0][df] = __builtin_amdgcn_mfma_f32_16x16x16f16(va[df], pfrag[0][nf], o[0][df],0,0,0);
        o[1][df] = __builtin_amdgcn_mfma_f32_16x16x16f16(va[df], pfrag[1][nf], o[1][df],0,0,0);
      }
      __builtin_amdgcn_s_setprio(0);
    }

    // one barrier per iteration: drains gloads (next tile) + all LDS reads
    __syncthreads();
    cur ^= 1;
  }

  // epilogue: cross-lane lsum reduce, then AO = O/lsum
  #pragma unroll
  for (int qm=0; qm<2; ++qm) {
    float rs = lrun[qm];
    rs += __shfl_xor(rs, 16, 64);
    rs += __shfl_xor(rs, 32, 64);
    float inv = 1.0f / rs;
    int qrow = n*SEQ + qt*128 + w*32 + qm*16 + q;
    #pragma unroll
    for (int df=0; df<4; ++df)
      #pragma unroll
      for (int r=0;r<4;++r)
        AO[(size_t)qrow*1024 + h*64 + df*16 + g*4 + r] = f32_to_f16u(o[qm][df][r] * inv);
  }
}

extern "C" void kernel_launch(void* const* d_in, const int* in_sizes, int n_in,
                              void* d_out, int out_size, void* d_ws, size_t ws_size,
                              hipStream_t stream)
{
  (void)in_sizes; (void)n_in; (void)out_size; (void)ws_size;
  const float* query = (const float*)d_in[0];
  const float* key   = (const float*)d_in[1];
  const float* value = (const float*)d_in[2];
  const float* Wq = (const float*)d_in[3];
  const float* bq = (const float*)d_in[4];
  const float* Wk = (const float*)d_in[5];
  const float* bk = (const float*)d_in[6];
  const float* Wv = (const float*)d_in[7];
  const float* bv = (const float*)d_in[8];
  const float* Wo = (const float*)d_in[9];
  const float* bo = (const float*)d_in[10];
  float* out = (float*)d_out;

  unsigned short* ws = (unsigned short*)d_ws;
  const size_t PLANE = (size_t)MROWS * 1024;
  unsigned short* Qf = ws;
  unsigned short* Kf = Qf + PLANE;
  unsigned short* Vt = Kf + PLANE;   // [ (n*16+h)*64+d ][ s ]
  unsigned short* AO = Vt + PLANE;
  unsigned short* WF = AO + PLANE;   // 4 x 1024x1024 f16 weight planes

  dim3 bb(256);
  wconv_k<<<dim3(512,4), bb, 0, stream>>>(Wq, Wk, Wv, Wo, WF);
  qkv_k <<<dim3(64,8,3), bb, 0, stream>>>(query,key,value, WF, bq,bk,bv, Qf,Kf,Vt);
  attn_k<<<dim3(1024), bb, 0, stream>>>(Qf, Kf, Vt, AO);
  oproj_k<<<dim3(64,8), bb, 0, stream>>>(AO, WF + 3*1048576, bo, out);
}

// Round 11
// 236.318 us; speedup vs baseline: 1.0302x; 1.0302x over previous
//
#include <hip/hip_runtime.h>
#include <stdint.h>

#define SEQ 2048
#define MROWS 8192
#define LOG2E 1.44269504f

typedef __attribute__((ext_vector_type(8))) _Float16 f16x8;
typedef __attribute__((ext_vector_type(2))) __fp16 fp16x2_t;   // cvt_pkrtz return type
typedef __attribute__((ext_vector_type(8))) unsigned short ushort8;
typedef __attribute__((ext_vector_type(4))) unsigned short ushort4_t;
typedef __attribute__((ext_vector_type(4))) float f32x4;

__device__ __forceinline__ unsigned short f32_to_f16u(float f) {
  union { _Float16 h; unsigned short u; } v; v.h = (_Float16)f; return v.u;
}

__device__ __forceinline__ ushort8 pack8_rtz(float4 f0, float4 f1) {
  union { fp16x2_t h2[4]; ushort8 u8; } pk;
  pk.h2[0] = __builtin_amdgcn_cvt_pkrtz(f0.x, f0.y);
  pk.h2[1] = __builtin_amdgcn_cvt_pkrtz(f0.z, f0.w);
  pk.h2[2] = __builtin_amdgcn_cvt_pkrtz(f1.x, f1.y);
  pk.h2[3] = __builtin_amdgcn_cvt_pkrtz(f1.z, f1.w);
  return pk.u8;
}

// async global(16B/lane) -> LDS (wave-uniform base + lane*16)
__device__ __forceinline__ void gload16(const void* g, void* l) {
  __builtin_amdgcn_global_load_lds(
      (const __attribute__((address_space(1))) unsigned int*)g,
      (__attribute__((address_space(3))) unsigned int*)l, 16, 0, 0);
}

// ---------------- W f32 -> f16 conversion (4 planes of 1024x1024) ----------
__global__ __launch_bounds__(256) void wconv_k(
    const float* __restrict__ Wq, const float* __restrict__ Wk,
    const float* __restrict__ Wv, const float* __restrict__ Wo,
    unsigned short* __restrict__ WF)
{
  const int plane = blockIdx.y;
  const float* __restrict__ s = (plane==0)? Wq : (plane==1)? Wk : (plane==2)? Wv : Wo;
  size_t off = ((size_t)blockIdx.x*256 + threadIdx.x) * 8;
  float4 f0 = *(const float4*)(s + off);
  float4 f1 = *(const float4*)(s + off + 4);
  *(ushort8*)&WF[(size_t)plane*1048576 + off] = pack8_rtz(f0, f1);
}

// ---------------- fused QKV projection GEMM ----------------
// z=0: Q -> f16 plane (scaled by log2e); z=1: K; z=2: V -> per-head transposed
// A (f32) staged manually with cvt_pkrtz; B (f16 plane) via global_load_lds.
__global__ __launch_bounds__(256) void qkv_k(
    const float* __restrict__ Aq, const float* __restrict__ Ak, const float* __restrict__ Av,
    const unsigned short* __restrict__ WF,
    const float* __restrict__ bq, const float* __restrict__ bk, const float* __restrict__ bv,
    unsigned short* __restrict__ Qf, unsigned short* __restrict__ Kf, unsigned short* __restrict__ Vt)
{
  const int z = blockIdx.z;
  const float* __restrict__ A    = (z==0)? Aq : (z==1)? Ak : Av;
  const unsigned short* __restrict__ W = WF + (size_t)z*1048576;
  const float* __restrict__ bias = (z==0)? bq : (z==1)? bk : bv;

  __shared__ unsigned short Ah[128*32];
  __shared__ unsigned short Bh[128*32];

  const int tid  = threadIdx.x;
  const int lane = tid & 63;
  const int w    = tid >> 6;
  const int wm   = w >> 1, wn = w & 1;
  const int row0 = blockIdx.x * 128;
  const int col0 = blockIdx.y * 128;

  f32x4 acc[4][4] = {};

  for (int k0 = 0; k0 < 1024; k0 += 32) {
    __syncthreads();
    // ---- B tile via global_load_lds (pre-swizzled source, linear dest) ----
    #pragma unroll
    for (int j=0;j<2;++j) {
      int r  = w*32 + j*16 + (lane>>2);
      int sl = (lane & 3) ^ ((r>>1)&3);
      gload16(W + (size_t)(col0 + r)*1024 + k0 + sl*8, &Bh[(w*32 + j*16)*32]);
    }
    // ---- A tile manual (f32 -> f16 cvt_pkrtz) ----
    #pragma unroll
    for (int i = 0; i < 2; ++i) {
      int c = tid + i*256;            // 0..511 chunks of 8 elements
      int r = c >> 2, slot = c & 3;   // 128 rows x 4 slots
      int lidx = r*32 + ((slot ^ ((r >> 1) & 3))*8);
      const float* ap = A + (size_t)(row0 + r)*1024 + k0 + slot*8;
      float4 f0 = *(const float4*)ap;
      float4 f1 = *(const float4*)(ap + 4);
      *(ushort8*)&Ah[lidx] = pack8_rtz(f0, f1);
    }
    __syncthreads();

    f16x8 a_[4], b_[4];
    const int slotR = lane >> 4;
    #pragma unroll
    for (int m=0;m<4;++m) {
      int r = wm*64 + m*16 + (lane & 15);
      a_[m] = *(const f16x8*)&Ah[r*32 + ((slotR ^ ((r>>1)&3))*8)];
    }
    #pragma unroll
    for (int nn=0;nn<4;++nn) {
      int r = wn*64 + nn*16 + (lane & 15);
      b_[nn] = *(const f16x8*)&Bh[r*32 + ((slotR ^ ((r>>1)&3))*8)];
    }
    #pragma unroll
    for (int m=0;m<4;++m)
      #pragma unroll
      for (int nn=0;nn<4;++nn)
        acc[m][nn] = __builtin_amdgcn_mfma_f32_16x16x32_f16(a_[m], b_[nn], acc[m][nn],0,0,0);
  }

  // epilogue (C frag: col=lane&15, row=(lane>>4)*4+r)
  #pragma unroll
  for (int m=0;m<4;++m) {
    #pragma unroll
    for (int nn=0;nn<4;++nn) {
      int gcol = col0 + wn*64 + nn*16 + (lane & 15);
      float bsv = bias[gcol];
      if (z == 2) {
        int rbase = row0 + wm*64 + m*16 + (lane>>4)*4;
        int nIdx = rbase >> 11, s0 = rbase & 2047;
        ushort4_t pk;
        #pragma unroll
        for (int r2=0;r2<4;++r2) pk[r2] = f32_to_f16u(acc[m][nn][r2] + bsv);
        *(ushort4_t*)&Vt[((size_t)(nIdx*1024 + gcol))*2048 + s0] = pk;
      } else {
        unsigned short* __restrict__ dst = (z==0)? Qf : Kf;
        const float qsc = (z==0)? LOG2E : 1.0f;   // fold log2(e) into Q
        #pragma unroll
        for (int r2=0;r2<4;++r2) {
          int grow = row0 + wm*64 + m*16 + (lane>>4)*4 + r2;
          dst[(size_t)grow*1024 + gcol] = f32_to_f16u((acc[m][nn][r2] + bsv) * qsc);
        }
      }
    }
  }
}

// ---------------- output projection: out = AO(f16) @ WoF^T + bo (f32) ------
// BOTH operands staged via global_load_lds.
__global__ __launch_bounds__(256) void oproj_k(
    const unsigned short* __restrict__ AO, const unsigned short* __restrict__ W,
    const float* __restrict__ bias, float* __restrict__ out)
{
  __shared__ unsigned short Ah[128*32];
  __shared__ unsigned short Bh[128*32];

  const int tid  = threadIdx.x;
  const int lane = tid & 63;
  const int w    = tid >> 6;
  const int wm   = w >> 1, wn = w & 1;
  const int row0 = blockIdx.x * 128;
  const int col0 = blockIdx.y * 128;

  f32x4 acc[4][4] = {};

  for (int k0 = 0; k0 < 1024; k0 += 32) {
    __syncthreads();
    #pragma unroll
    for (int j=0;j<2;++j) {
      int r  = w*32 + j*16 + (lane>>2);
      int sl = (lane & 3) ^ ((r>>1)&3);
      gload16(AO + (size_t)(row0 + r)*1024 + k0 + sl*8, &Ah[(w*32 + j*16)*32]);
      gload16(W  + (size_t)(col0 + r)*1024 + k0 + sl*8, &Bh[(w*32 + j*16)*32]);
    }
    __syncthreads();

    f16x8 a_[4], b_[4];
    const int slotR = lane >> 4;
    #pragma unroll
    for (int m=0;m<4;++m) {
      int r = wm*64 + m*16 + (lane & 15);
      a_[m] = *(const f16x8*)&Ah[r*32 + ((slotR ^ ((r>>1)&3))*8)];
    }
    #pragma unroll
    for (int nn=0;nn<4;++nn) {
      int r = wn*64 + nn*16 + (lane & 15);
      b_[nn] = *(const f16x8*)&Bh[r*32 + ((slotR ^ ((r>>1)&3))*8)];
    }
    #pragma unroll
    for (int m=0;m<4;++m)
      #pragma unroll
      for (int nn=0;nn<4;++nn)
        acc[m][nn] = __builtin_amdgcn_mfma_f32_16x16x32_f16(a_[m], b_[nn], acc[m][nn],0,0,0);
  }

  #pragma unroll
  for (int m=0;m<4;++m)
    #pragma unroll
    for (int nn=0;nn<4;++nn) {
      int gcol = col0 + wn*64 + nn*16 + (lane & 15);
      float bsv = bias[gcol];
      #pragma unroll
      for (int r2=0;r2<4;++r2) {
        int grow = row0 + wm*64 + m*16 + (lane>>4)*4 + r2;
        out[(size_t)grow*1024 + gcol] = acc[m][nn][r2] + bsv;
      }
    }
}

// ---------------- Flash attention: r8 structure + gload_lds K/V staging ----
// grid 1024 blocks (16 q-tiles of 128 x 64 heads), XCD-swizzled.
// 4 waves x 32 q-rows (qm=0,1); KVBLK=64, K/V double-buffered via
// global_load_lds (pre-swizzled source, linear dest), 1 barrier/iter.
// QK^T as mfma(K,Q) 16x16x32 -> S^T (lane owns q=lane&15).
// PV as mfma(V^T, P) 16x16x32 with P via wave-private LDS (32 rows);
// V fragments read once, feed both qm halves.
// Defer-max (T13); lrun kept lane-partial until the epilogue.
__global__ __launch_bounds__(256) void attn_k(
  const unsigned short* __restrict__ Qf, const unsigned short* __restrict__ Kf,
  const unsigned short* __restrict__ Vt, unsigned short* __restrict__ AO)
{
  __shared__ unsigned short Ks[2][64*64];   // K tile (swizzled)      16 KB
  __shared__ unsigned short Vs[2][64*64];   // V^T tile (swizzled)    16 KB
  __shared__ unsigned short Ps[4][32*64];   // per-wave P (32 q rows) 16 KB

  const int tid = threadIdx.x, lane = tid & 63, w = tid >> 6;
  const int q = lane & 15, g = lane >> 4;

  // T1 XCD swizzle (bijective: 1024 % 8 == 0)
  const int bid = blockIdx.x;
  const int swz = (bid & 7) * 128 + (bid >> 3);
  const int qt = swz & 15, nh = swz >> 4;
  const int n = nh >> 4, h = nh & 15;

  // Q fragments (pre-scaled by log2e), 2 q-subtiles of 16 rows
  f16x8 qf[2][2];
  #pragma unroll
  for (int qm=0; qm<2; ++qm) {
    int qrow = n*SEQ + qt*128 + w*32 + qm*16 + q;
    #pragma unroll
    for (int ks=0; ks<2; ++ks)
      qf[qm][ks] = *(const f16x8*)&Qf[(size_t)qrow*1024 + h*64 + ks*32 + g*8];
  }

  f32x4 o[2][4] = {};       // O^T frags: o[qm][df][r] = O[q][d=df*16+4g+r]
  float mrun[2] = {-1e30f,-1e30f}, lrun[2] = {0.f,0.f};  // lrun = LANE-partial

  const size_t kbase = (size_t)(n*SEQ)*1024 + h*64;   // K plane [s][1024]
  const size_t vbase = ((size_t)(n*1024 + h*64))*SEQ; // Vt [d][s]

  // staging geometry: each gload16 covers 8 rows x 128B (wave-linear dest);
  // source granule pre-swizzled so LDS[row][p] = global[row][p ^ (row&7)]
  const int srow = lane >> 3;              // row within 8-row group (= r&7)
  const int ssl  = (lane & 7) ^ srow;      // pre-swizzled 16B granule

  // prologue: stage K/V tile 0
  #pragma unroll
  for (int j=0;j<2;++j) {
    int r = w*16 + j*8 + srow;
    gload16(&Kf[kbase + (size_t)r*1024 + ssl*8], &Ks[0][(w*16+j*8)*64]);
    gload16(&Vt[vbase + (size_t)r*SEQ  + ssl*8], &Vs[0][(w*16+j*8)*64]);
  }
  __syncthreads();

  int cur = 0;
  for (int kt = 0; kt < 32; ++kt) {
    // ---- issue next tile's staging now; drains at this iter's barrier ----
    if (kt < 31) {
      #pragma unroll
      for (int j=0;j<2;++j) {
        int r = w*16 + j*8 + srow;
        gload16(&Kf[kbase + (size_t)((kt+1)*64 + r)*1024 + ssl*8], &Ks[cur^1][(w*16+j*8)*64]);
        gload16(&Vt[vbase + (size_t)r*SEQ + (kt+1)*64 + ssl*8],    &Vs[cur^1][(w*16+j*8)*64]);
      }
    }

    // ---- S^T = K * Q^T : s[qm][nf][r] = S[q][k = nf*16 + 4g + r] ----
    f32x4 s[2][4];
    #pragma unroll
    for (int qm=0;qm<2;++qm)
      #pragma unroll
      for (int nf=0; nf<4; ++nf) s[qm][nf] = f32x4{0.f,0.f,0.f,0.f};
    __builtin_amdgcn_s_setprio(1);
    #pragma unroll
    for (int nf=0; nf<4; ++nf) {
      int rr = nf*16 + q;
      #pragma unroll
      for (int ks=0; ks<2; ++ks) {
        f16x8 kb = *(const f16x8*)&Ks[cur][rr*64 + (((ks*4+g)^(q&7))*8)];
        s[0][nf] = __builtin_amdgcn_mfma_f32_16x16x32_f16(kb, qf[0][ks], s[0][nf],0,0,0);
        s[1][nf] = __builtin_amdgcn_mfma_f32_16x16x32_f16(kb, qf[1][ks], s[1][nf],0,0,0);
      }
    }
    __builtin_amdgcn_s_setprio(0);

    // ---- softmax per q-subtile (defer-max), P pack to 32-row buffer ----
    #pragma unroll
    for (int qm=0; qm<2; ++qm) {
      float ml = fmaxf(fmaxf(fmaxf(s[qm][0][0],s[qm][0][1]),fmaxf(s[qm][0][2],s[qm][0][3])),
                       fmaxf(fmaxf(s[qm][1][0],s[qm][1][1]),fmaxf(s[qm][1][2],s[qm][1][3])));
      float mh = fmaxf(fmaxf(fmaxf(s[qm][2][0],s[qm][2][1]),fmaxf(s[qm][2][2],s[qm][2][3])),
                       fmaxf(fmaxf(s[qm][3][0],s[qm][3][1]),fmaxf(s[qm][3][2],s[qm][3][3])));
      ml = fmaxf(ml, mh);
      if (!__all(ml <= mrun[qm] + 7.0f)) {
        // slow path: grow running max, rescale O and lane-partial lsum
        float m1 = fmaxf(ml, __shfl_xor(ml, 16, 64));
        float m2 = fmaxf(m1, __shfl_xor(m1, 32, 64));
        float mn = fmaxf(mrun[qm], m2);
        float sc = __builtin_amdgcn_exp2f(mrun[qm] - mn);
        lrun[qm] *= sc;
        mrun[qm] = mn;
        #pragma unroll
        for (int df=0; df<4; ++df)
          #pragma unroll
          for (int r=0;r<4;++r) o[qm][df][r] *= sc;
      }
      float m0 = mrun[qm];
      float pvv[16]; float rsl = 0.f;
      #pragma unroll
      for (int nf=0; nf<4; ++nf)
        #pragma unroll
        for (int r=0;r<4;++r) {
          float p = __builtin_amdgcn_exp2f(s[qm][nf][r] - m0);
          pvv[nf*4+r] = p; rsl += p;
        }
      lrun[qm] += rsl;          // lane-partial; cross-lane reduce at epilogue

      #pragma unroll
      for (int nf=0; nf<4; ++nf) {
        union { fp16x2_t h2[2]; ushort4_t u4; } pk;
        pk.h2[0] = __builtin_amdgcn_cvt_pkrtz(pvv[nf*4+0], pvv[nf*4+1]);
        pk.h2[1] = __builtin_amdgcn_cvt_pkrtz(pvv[nf*4+2], pvv[nf*4+3]);
        int gi = 2*nf + (g>>1);                       // 16B granule index
        int idx = (qm*16+q)*64 + ((gi ^ (q&7))*8) + (g&1)*4;
        *(ushort4_t*)&Ps[w][idx] = pk.u4;
      }
    }

    // ---- O^T += V^T * P  (V fragment read once, feeds both qm) ----
    #pragma unroll
    for (int s2=0; s2<2; ++s2) {
      int sl = 4*s2 + g;
      f16x8 pa0 = *(const f16x8*)&Ps[w][(q    )*64 + ((sl^(q&7))*8)];
      f16x8 pa1 = *(const f16x8*)&Ps[w][(16+q)*64 + ((sl^(q&7))*8)];
      __builtin_amdgcn_s_setprio(1);
      #pragma unroll
      for (int df=0; df<4; ++df) {
        f16x8 vb = *(const f16x8*)&Vs[cur][(df*16+q)*64 + ((sl^(q&7))*8)];
        o[0][df] = __builtin_amdgcn_mfma_f32_16x16x32_f16(vb, pa0, o[0][df],0,0,0);
        o[1][df] = __builtin_amdgcn_mfma_f32_16x16x32_f16(vb, pa1, o[1][df],0,0,0);
      }
      __builtin_amdgcn_s_setprio(0);
    }

    // one barrier per iteration: drains gloads (next tile) + all LDS traffic
    __syncthreads();
    cur ^= 1;
  }

  // epilogue: cross-lane lsum reduce, then AO = O/lsum
  #pragma unroll
  for (int qm=0; qm<2; ++qm) {
    float rs = lrun[qm];
    rs += __shfl_xor(rs, 16, 64);
    rs += __shfl_xor(rs, 32, 64);
    float inv = 1.0f / rs;
    int qrow = n*SEQ + qt*128 + w*32 + qm*16 + q;
    #pragma unroll
    for (int df=0; df<4; ++df)
      #pragma unroll
      for (int r=0;r<4;++r)
        AO[(size_t)qrow*1024 + h*64 + df*16 + g*4 + r] = f32_to_f16u(o[qm][df][r] * inv);
  }
}

extern "C" void kernel_launch(void* const* d_in, const int* in_sizes, int n_in,
                              void* d_out, int out_size, void* d_ws, size_t ws_size,
                              hipStream_t stream)
{
  (void)in_sizes; (void)n_in; (void)out_size; (void)ws_size;
  const float* query = (const float*)d_in[0];
  const float* key   = (const float*)d_in[1];
  const float* value = (const float*)d_in[2];
  const float* Wq = (const float*)d_in[3];
  const float* bq = (const float*)d_in[4];
  const float* Wk = (const float*)d_in[5];
  const float* bk = (const float*)d_in[6];
  const float* Wv = (const float*)d_in[7];
  const float* bv = (const float*)d_in[8];
  const float* Wo = (const float*)d_in[9];
  const float* bo = (const float*)d_in[10];
  float* out = (float*)d_out;

  unsigned short* ws = (unsigned short*)d_ws;
  const size_t PLANE = (size_t)MROWS * 1024;
  unsigned short* Qf = ws;
  unsigned short* Kf = Qf + PLANE;
  unsigned short* Vt = Kf + PLANE;   // [ (n*16+h)*64+d ][ s ]
  unsigned short* AO = Vt + PLANE;
  unsigned short* WF = AO + PLANE;   // 4 x 1024x1024 f16 weight planes

  dim3 bb(256);
  wconv_k<<<dim3(512,4), bb, 0, stream>>>(Wq, Wk, Wv, Wo, WF);
  qkv_k <<<dim3(64,8,3), bb, 0, stream>>>(query,key,value, WF, bq,bk,bv, Qf,Kf,Vt);
  attn_k<<<dim3(1024), bb, 0, stream>>>(Qf, Kf, Vt, AO);
  oproj_k<<<dim3(64,8), bb, 0, stream>>>(AO, WF + 3*1048576, bo, out);
}

// Round 12
// 233.914 us; speedup vs baseline: 1.0407x; 1.0103x over previous
//
#include <hip/hip_runtime.h>
#include <stdint.h>

#define SEQ 2048
#define MROWS 8192
#define LOG2E 1.44269504f

typedef __attribute__((ext_vector_type(8))) _Float16 f16x8;
typedef __attribute__((ext_vector_type(2))) __fp16 fp16x2_t;   // cvt_pkrtz return type
typedef __attribute__((ext_vector_type(8))) unsigned short ushort8;
typedef __attribute__((ext_vector_type(4))) unsigned short ushort4_t;
typedef __attribute__((ext_vector_type(4))) float f32x4;

__device__ __forceinline__ unsigned short f32_to_f16u(float f) {
  union { _Float16 h; unsigned short u; } v; v.h = (_Float16)f; return v.u;
}

__device__ __forceinline__ ushort8 pack8_rtz(float4 f0, float4 f1) {
  union { fp16x2_t h2[4]; ushort8 u8; } pk;
  pk.h2[0] = __builtin_amdgcn_cvt_pkrtz(f0.x, f0.y);
  pk.h2[1] = __builtin_amdgcn_cvt_pkrtz(f0.z, f0.w);
  pk.h2[2] = __builtin_amdgcn_cvt_pkrtz(f1.x, f1.y);
  pk.h2[3] = __builtin_amdgcn_cvt_pkrtz(f1.z, f1.w);
  return pk.u8;
}

// async global(16B/lane) -> LDS (wave-uniform base + lane*16)
__device__ __forceinline__ void gload16(const void* g, void* l) {
  __builtin_amdgcn_global_load_lds(
      (const __attribute__((address_space(1))) unsigned int*)g,
      (__attribute__((address_space(3))) unsigned int*)l, 16, 0, 0);
}

// ---------------- W f32 -> f16 conversion (4 planes of 1024x1024) ----------
__global__ __launch_bounds__(256) void wconv_k(
    const float* __restrict__ Wq, const float* __restrict__ Wk,
    const float* __restrict__ Wv, const float* __restrict__ Wo,
    unsigned short* __restrict__ WF)
{
  const int plane = blockIdx.y;
  const float* __restrict__ s = (plane==0)? Wq : (plane==1)? Wk : (plane==2)? Wv : Wo;
  size_t off = ((size_t)blockIdx.x*256 + threadIdx.x) * 8;
  float4 f0 = *(const float4*)(s + off);
  float4 f1 = *(const float4*)(s + off + 4);
  *(ushort8*)&WF[(size_t)plane*1048576 + off] = pack8_rtz(f0, f1);
}

// ---------------- fused QKV projection GEMM ----------------
// z=0: Q -> f16 plane (scaled by log2e); z=1: K; z=2: V -> per-head transposed
// A (f32) staged manually with cvt_pkrtz; B (f16 plane) via global_load_lds.
__global__ __launch_bounds__(256) void qkv_k(
    const float* __restrict__ Aq, const float* __restrict__ Ak, const float* __restrict__ Av,
    const unsigned short* __restrict__ WF,
    const float* __restrict__ bq, const float* __restrict__ bk, const float* __restrict__ bv,
    unsigned short* __restrict__ Qf, unsigned short* __restrict__ Kf, unsigned short* __restrict__ Vt)
{
  const int z = blockIdx.z;
  const float* __restrict__ A    = (z==0)? Aq : (z==1)? Ak : Av;
  const unsigned short* __restrict__ W = WF + (size_t)z*1048576;
  const float* __restrict__ bias = (z==0)? bq : (z==1)? bk : bv;

  __shared__ unsigned short Ah[128*32];
  __shared__ unsigned short Bh[128*32];

  const int tid  = threadIdx.x;
  const int lane = tid & 63;
  const int w    = tid >> 6;
  const int wm   = w >> 1, wn = w & 1;
  const int row0 = blockIdx.x * 128;
  const int col0 = blockIdx.y * 128;

  f32x4 acc[4][4] = {};

  for (int k0 = 0; k0 < 1024; k0 += 32) {
    __syncthreads();
    // ---- B tile via global_load_lds (pre-swizzled source, linear dest) ----
    #pragma unroll
    for (int j=0;j<2;++j) {
      int r  = w*32 + j*16 + (lane>>2);
      int sl = (lane & 3) ^ ((r>>1)&3);
      gload16(W + (size_t)(col0 + r)*1024 + k0 + sl*8, &Bh[(w*32 + j*16)*32]);
    }
    // ---- A tile manual (f32 -> f16 cvt_pkrtz) ----
    #pragma unroll
    for (int i = 0; i < 2; ++i) {
      int c = tid + i*256;            // 0..511 chunks of 8 elements
      int r = c >> 2, slot = c & 3;   // 128 rows x 4 slots
      int lidx = r*32 + ((slot ^ ((r >> 1) & 3))*8);
      const float* ap = A + (size_t)(row0 + r)*1024 + k0 + slot*8;
      float4 f0 = *(const float4*)ap;
      float4 f1 = *(const float4*)(ap + 4);
      *(ushort8*)&Ah[lidx] = pack8_rtz(f0, f1);
    }
    __syncthreads();

    f16x8 a_[4], b_[4];
    const int slotR = lane >> 4;
    #pragma unroll
    for (int m=0;m<4;++m) {
      int r = wm*64 + m*16 + (lane & 15);
      a_[m] = *(const f16x8*)&Ah[r*32 + ((slotR ^ ((r>>1)&3))*8)];
    }
    #pragma unroll
    for (int nn=0;nn<4;++nn) {
      int r = wn*64 + nn*16 + (lane & 15);
      b_[nn] = *(const f16x8*)&Bh[r*32 + ((slotR ^ ((r>>1)&3))*8)];
    }
    #pragma unroll
    for (int m=0;m<4;++m)
      #pragma unroll
      for (int nn=0;nn<4;++nn)
        acc[m][nn] = __builtin_amdgcn_mfma_f32_16x16x32_f16(a_[m], b_[nn], acc[m][nn],0,0,0);
  }

  // epilogue (C frag: col=lane&15, row=(lane>>4)*4+r)
  #pragma unroll
  for (int m=0;m<4;++m) {
    #pragma unroll
    for (int nn=0;nn<4;++nn) {
      int gcol = col0 + wn*64 + nn*16 + (lane & 15);
      float bsv = bias[gcol];
      if (z == 2) {
        int rbase = row0 + wm*64 + m*16 + (lane>>4)*4;
        int nIdx = rbase >> 11, s0 = rbase & 2047;
        ushort4_t pk;
        #pragma unroll
        for (int r2=0;r2<4;++r2) pk[r2] = f32_to_f16u(acc[m][nn][r2] + bsv);
        *(ushort4_t*)&Vt[((size_t)(nIdx*1024 + gcol))*2048 + s0] = pk;
      } else {
        unsigned short* __restrict__ dst = (z==0)? Qf : Kf;
        const float qsc = (z==0)? LOG2E : 1.0f;   // fold log2(e) into Q
        #pragma unroll
        for (int r2=0;r2<4;++r2) {
          int grow = row0 + wm*64 + m*16 + (lane>>4)*4 + r2;
          dst[(size_t)grow*1024 + gcol] = f32_to_f16u((acc[m][nn][r2] + bsv) * qsc);
        }
      }
    }
  }
}

// ---------------- output projection: out = AO(f16) @ WoF^T + bo (f32) ------
// BOTH operands staged via global_load_lds.
__global__ __launch_bounds__(256) void oproj_k(
    const unsigned short* __restrict__ AO, const unsigned short* __restrict__ W,
    const float* __restrict__ bias, float* __restrict__ out)
{
  __shared__ unsigned short Ah[128*32];
  __shared__ unsigned short Bh[128*32];

  const int tid  = threadIdx.x;
  const int lane = tid & 63;
  const int w    = tid >> 6;
  const int wm   = w >> 1, wn = w & 1;
  const int row0 = blockIdx.x * 128;
  const int col0 = blockIdx.y * 128;

  f32x4 acc[4][4] = {};

  for (int k0 = 0; k0 < 1024; k0 += 32) {
    __syncthreads();
    #pragma unroll
    for (int j=0;j<2;++j) {
      int r  = w*32 + j*16 + (lane>>2);
      int sl = (lane & 3) ^ ((r>>1)&3);
      gload16(AO + (size_t)(row0 + r)*1024 + k0 + sl*8, &Ah[(w*32 + j*16)*32]);
      gload16(W  + (size_t)(col0 + r)*1024 + k0 + sl*8, &Bh[(w*32 + j*16)*32]);
    }
    __syncthreads();

    f16x8 a_[4], b_[4];
    const int slotR = lane >> 4;
    #pragma unroll
    for (int m=0;m<4;++m) {
      int r = wm*64 + m*16 + (lane & 15);
      a_[m] = *(const f16x8*)&Ah[r*32 + ((slotR ^ ((r>>1)&3))*8)];
    }
    #pragma unroll
    for (int nn=0;nn<4;++nn) {
      int r = wn*64 + nn*16 + (lane & 15);
      b_[nn] = *(const f16x8*)&Bh[r*32 + ((slotR ^ ((r>>1)&3))*8)];
    }
    #pragma unroll
    for (int m=0;m<4;++m)
      #pragma unroll
      for (int nn=0;nn<4;++nn)
        acc[m][nn] = __builtin_amdgcn_mfma_f32_16x16x32_f16(a_[m], b_[nn], acc[m][nn],0,0,0);
  }

  #pragma unroll
  for (int m=0;m<4;++m)
    #pragma unroll
    for (int nn=0;nn<4;++nn) {
      int gcol = col0 + wn*64 + nn*16 + (lane & 15);
      float bsv = bias[gcol];
      #pragma unroll
      for (int r2=0;r2<4;++r2) {
        int grow = row0 + wm*64 + m*16 + (lane>>4)*4 + r2;
        out[(size_t)grow*1024 + gcol] = acc[m][nn][r2] + bsv;
      }
    }
}

// ---------------- Flash attention: 40KB LDS (Ks dbuf + Vs single + Ps) -----
// grid 1024 blocks (16 q-tiles of 128 x 64 heads), XCD-swizzled -> with
// 40KB/block, 4 blocks/CU: ALL 1024 blocks co-resident, zero tail.
// 4 waves x 32 q-rows (qm=0,1); KVBLK=64; reg-staged prefetch (r11 showed
// gload_lds loses here). K(t+1) written to idle K buffer pre-PV (no sync);
// V single-buffered: barrier1 (PV reads done) -> V write -> barrier2.
// QK^T as mfma(K,Q) -> S^T; PV as mfma(V^T,P) -> O^T; defer-max (T13);
// lrun lane-partial until epilogue.
__global__ __launch_bounds__(256) void attn_k(
  const unsigned short* __restrict__ Qf, const unsigned short* __restrict__ Kf,
  const unsigned short* __restrict__ Vt, unsigned short* __restrict__ AO)
{
  __shared__ unsigned short Ks[2][64*64];   // K tile dbuf (swizzled) 16 KB
  __shared__ unsigned short Vs[64*64];      // V^T tile (swizzled)     8 KB
  __shared__ unsigned short Ps[4][32*64];   // per-wave P (32 q rows) 16 KB

  const int tid = threadIdx.x, lane = tid & 63, w = tid >> 6;
  const int q = lane & 15, g = lane >> 4;

  // T1 XCD swizzle (bijective: 1024 % 8 == 0)
  const int bid = blockIdx.x;
  const int swz = (bid & 7) * 128 + (bid >> 3);
  const int qt = swz & 15, nh = swz >> 4;
  const int n = nh >> 4, h = nh & 15;

  // Q fragments (pre-scaled by log2e), 2 q-subtiles of 16 rows
  f16x8 qf[2][2];
  #pragma unroll
  for (int qm=0; qm<2; ++qm) {
    int qrow = n*SEQ + qt*128 + w*32 + qm*16 + q;
    #pragma unroll
    for (int ks=0; ks<2; ++ks)
      qf[qm][ks] = *(const f16x8*)&Qf[(size_t)qrow*1024 + h*64 + ks*32 + g*8];
  }

  f32x4 o[2][4] = {};       // O^T frags: o[qm][df][r] = O[q][d=df*16+4g+r]
  float mrun[2] = {-1e30f,-1e30f}, lrun[2] = {0.f,0.f};  // lrun = LANE-partial

  const size_t kbase = (size_t)(n*SEQ)*1024 + h*64;   // K plane [s][1024]
  const size_t vbase = ((size_t)(n*1024 + h*64))*SEQ; // Vt [d][s]

  // prologue: stage K/V tile 0 (64 x 64, 8-slot XOR swizzle)
  #pragma unroll
  for (int i=0;i<2;++i){
    int c = tid + i*256; int r = c>>3, sl = c&7;
    int lidx = r*64 + ((sl^(r&7))*8);
    *(ushort8*)&Ks[0][lidx] = *(const ushort8*)&Kf[kbase + (size_t)r*1024 + sl*8];
    *(ushort8*)&Vs[lidx]    = *(const ushort8*)&Vt[vbase + (size_t)r*SEQ + sl*8];
  }
  __syncthreads();

  int cur = 0;
  for (int kt = 0; kt < 32; ++kt) {
    // ---- prefetch next K/V tile to regs (hides under this iteration) ----
    ushort8 kreg[2], vreg[2];
    if (kt < 31) {
      #pragma unroll
      for (int i=0;i<2;++i){
        int c = tid + i*256; int r = c>>3, sl = c&7;
        kreg[i] = *(const ushort8*)&Kf[kbase + (size_t)((kt+1)*64 + r)*1024 + sl*8];
        vreg[i] = *(const ushort8*)&Vt[vbase + (size_t)r*SEQ + (kt+1)*64 + sl*8];
      }
    }

    // ---- S^T = K * Q^T : s[qm][nf][r] = S[q][k = nf*16 + 4g + r] ----
    f32x4 s[2][4];
    #pragma unroll
    for (int qm=0;qm<2;++qm)
      #pragma unroll
      for (int nf=0; nf<4; ++nf) s[qm][nf] = f32x4{0.f,0.f,0.f,0.f};
    __builtin_amdgcn_s_setprio(1);
    #pragma unroll
    for (int nf=0; nf<4; ++nf) {
      int rr = nf*16 + q;
      #pragma unroll
      for (int ks=0; ks<2; ++ks) {
        f16x8 kb = *(const f16x8*)&Ks[cur][rr*64 + (((ks*4+g)^(q&7))*8)];
        s[0][nf] = __builtin_amdgcn_mfma_f32_16x16x32_f16(kb, qf[0][ks], s[0][nf],0,0,0);
        s[1][nf] = __builtin_amdgcn_mfma_f32_16x16x32_f16(kb, qf[1][ks], s[1][nf],0,0,0);
      }
    }
    __builtin_amdgcn_s_setprio(0);

    // ---- write next K tile into the idle K buffer (no sync needed) ----
    if (kt < 31) {
      #pragma unroll
      for (int i=0;i<2;++i){
        int c = tid + i*256; int r = c>>3, sl = c&7;
        *(ushort8*)&Ks[cur^1][r*64 + ((sl^(r&7))*8)] = kreg[i];
      }
    }

    // ---- softmax per q-subtile (defer-max), P pack to 32-row buffer ----
    #pragma unroll
    for (int qm=0; qm<2; ++qm) {
      // max tree in max3-fusable triples (T17)
      float t0 = fmaxf(fmaxf(s[qm][0][0],s[qm][0][1]),s[qm][0][2]);
      float t1 = fmaxf(fmaxf(s[qm][0][3],s[qm][1][0]),s[qm][1][1]);
      float t2 = fmaxf(fmaxf(s[qm][1][2],s[qm][1][3]),s[qm][2][0]);
      float t3 = fmaxf(fmaxf(s[qm][2][1],s[qm][2][2]),s[qm][2][3]);
      float t4 = fmaxf(fmaxf(s[qm][3][0],s[qm][3][1]),s[qm][3][2]);
      float ml = fmaxf(fmaxf(fmaxf(t0,t1),fmaxf(t2,t3)), fmaxf(t4,s[qm][3][3]));
      if (!__all(ml <= mrun[qm] + 7.0f)) {
        // slow path: grow running max, rescale O and lane-partial lsum
        float m1 = fmaxf(ml, __shfl_xor(ml, 16, 64));
        float m2 = fmaxf(m1, __shfl_xor(m1, 32, 64));
        float mn = fmaxf(mrun[qm], m2);
        float sc = __builtin_amdgcn_exp2f(mrun[qm] - mn);
        lrun[qm] *= sc;
        mrun[qm] = mn;
        #pragma unroll
        for (int df=0; df<4; ++df)
          #pragma unroll
          for (int r=0;r<4;++r) o[qm][df][r] *= sc;
      }
      float m0 = mrun[qm];
      float pvv[16]; float rsl = 0.f;
      #pragma unroll
      for (int nf=0; nf<4; ++nf)
        #pragma unroll
        for (int r=0;r<4;++r) {
          float p = __builtin_amdgcn_exp2f(s[qm][nf][r] - m0);
          pvv[nf*4+r] = p; rsl += p;
        }
      lrun[qm] += rsl;          // lane-partial; cross-lane reduce at epilogue

      #pragma unroll
      for (int nf=0; nf<4; ++nf) {
        union { fp16x2_t h2[2]; ushort4_t u4; } pk;
        pk.h2[0] = __builtin_amdgcn_cvt_pkrtz(pvv[nf*4+0], pvv[nf*4+1]);
        pk.h2[1] = __builtin_amdgcn_cvt_pkrtz(pvv[nf*4+2], pvv[nf*4+3]);
        int gi = 2*nf + (g>>1);                       // 16B granule index
        int idx = (qm*16+q)*64 + ((gi ^ (q&7))*8) + (g&1)*4;
        *(ushort4_t*)&Ps[w][idx] = pk.u4;
      }
    }

    // ---- O^T += V^T * P  (V fragment read once, feeds both qm) ----
    #pragma unroll
    for (int s2=0; s2<2; ++s2) {
      int sl = 4*s2 + g;
      f16x8 pa0 = *(const f16x8*)&Ps[w][(q    )*64 + ((sl^(q&7))*8)];
      f16x8 pa1 = *(const f16x8*)&Ps[w][(16+q)*64 + ((sl^(q&7))*8)];
      __builtin_amdgcn_s_setprio(1);
      #pragma unroll
      for (int df=0; df<4; ++df) {
        f16x8 vb = *(const f16x8*)&Vs[(df*16+q)*64 + ((sl^(q&7))*8)];
        o[0][df] = __builtin_amdgcn_mfma_f32_16x16x32_f16(vb, pa0, o[0][df],0,0,0);
        o[1][df] = __builtin_amdgcn_mfma_f32_16x16x32_f16(vb, pa1, o[1][df],0,0,0);
      }
      __builtin_amdgcn_s_setprio(0);
    }

    // barrier1: all PV reads of Vs complete (and K writes visible for next)
    __syncthreads();
    if (kt < 31) {
      // write next V tile into the (single) V buffer, then release it
      #pragma unroll
      for (int i=0;i<2;++i){
        int c = tid + i*256; int r = c>>3, sl = c&7;
        *(ushort8*)&Vs[r*64 + ((sl^(r&7))*8)] = vreg[i];
      }
      __syncthreads();        // barrier2: Vs ready for next iteration
    }
    cur ^= 1;
  }

  // epilogue: cross-lane lsum reduce, then AO = O/lsum
  #pragma unroll
  for (int qm=0; qm<2; ++qm) {
    float rs = lrun[qm];
    rs += __shfl_xor(rs, 16, 64);
    rs += __shfl_xor(rs, 32, 64);
    float inv = 1.0f / rs;
    int qrow = n*SEQ + qt*128 + w*32 + qm*16 + q;
    #pragma unroll
    for (int df=0; df<4; ++df)
      #pragma unroll
      for (int r=0;r<4;++r)
        AO[(size_t)qrow*1024 + h*64 + df*16 + g*4 + r] = f32_to_f16u(o[qm][df][r] * inv);
  }
}

extern "C" void kernel_launch(void* const* d_in, const int* in_sizes, int n_in,
                              void* d_out, int out_size, void* d_ws, size_t ws_size,
                              hipStream_t stream)
{
  (void)in_sizes; (void)n_in; (void)out_size; (void)ws_size;
  const float* query = (const float*)d_in[0];
  const float* key   = (const float*)d_in[1];
  const float* value = (const float*)d_in[2];
  const float* Wq = (const float*)d_in[3];
  const float* bq = (const float*)d_in[4];
  const float* Wk = (const float*)d_in[5];
  const float* bk = (const float*)d_in[6];
  const float* Wv = (const float*)d_in[7];
  const float* bv = (const float*)d_in[8];
  const float* Wo = (const float*)d_in[9];
  const float* bo = (const float*)d_in[10];
  float* out = (float*)d_out;

  unsigned short* ws = (unsigned short*)d_ws;
  const size_t PLANE = (size_t)MROWS * 1024;
  unsigned short* Qf = ws;
  unsigned short* Kf = Qf + PLANE;
  unsigned short* Vt = Kf + PLANE;   // [ (n*16+h)*64+d ][ s ]
  unsigned short* AO = Vt + PLANE;
  unsigned short* WF = AO + PLANE;   // 4 x 1024x1024 f16 weight planes

  dim3 bb(256);
  wconv_k<<<dim3(512,4), bb, 0, stream>>>(Wq, Wk, Wv, Wo, WF);
  qkv_k <<<dim3(64,8,3), bb, 0, stream>>>(query,key,value, WF, bq,bk,bv, Qf,Kf,Vt);
  attn_k<<<dim3(1024), bb, 0, stream>>>(Qf, Kf, Vt, AO);
  oproj_k<<<dim3(64,8), bb, 0, stream>>>(AO, WF + 3*1048576, bo, out);
}

// Round 13
// 222.550 us; speedup vs baseline: 1.0939x; 1.0511x over previous
//
#include <hip/hip_runtime.h>
#include <stdint.h>

#define SEQ 2048
#define MROWS 8192
#define LOG2E 1.44269504f

typedef __attribute__((ext_vector_type(8))) _Float16 f16x8;
typedef __attribute__((ext_vector_type(2))) __fp16 fp16x2_t;   // cvt_pkrtz return type
typedef __attribute__((ext_vector_type(8))) unsigned short ushort8;
typedef __attribute__((ext_vector_type(4))) unsigned short ushort4_t;
typedef __attribute__((ext_vector_type(4))) float f32x4;
typedef __attribute__((ext_vector_type(16))) float f32x16;

__device__ __forceinline__ unsigned short f32_to_f16u(float f) {
  union { _Float16 h; unsigned short u; } v; v.h = (_Float16)f; return v.u;
}

__device__ __forceinline__ unsigned int pk_u32(float a, float b) {
  union { fp16x2_t h; unsigned int u; } v;
  v.h = __builtin_amdgcn_cvt_pkrtz(a, b);
  return v.u;
}

__device__ __forceinline__ ushort8 pack8_rtz(float4 f0, float4 f1) {
  union { fp16x2_t h2[4]; ushort8 u8; } pk;
  pk.h2[0] = __builtin_amdgcn_cvt_pkrtz(f0.x, f0.y);
  pk.h2[1] = __builtin_amdgcn_cvt_pkrtz(f0.z, f0.w);
  pk.h2[2] = __builtin_amdgcn_cvt_pkrtz(f1.x, f1.y);
  pk.h2[3] = __builtin_amdgcn_cvt_pkrtz(f1.z, f1.w);
  return pk.u8;
}

// async global(16B/lane) -> LDS (wave-uniform base + lane*16)
__device__ __forceinline__ void gload16(const void* g, void* l) {
  __builtin_amdgcn_global_load_lds(
      (const __attribute__((address_space(1))) unsigned int*)g,
      (__attribute__((address_space(3))) unsigned int*)l, 16, 0, 0);
}

// ---------------- W f32 -> f16 conversion (4 planes of 1024x1024) ----------
__global__ __launch_bounds__(256) void wconv_k(
    const float* __restrict__ Wq, const float* __restrict__ Wk,
    const float* __restrict__ Wv, const float* __restrict__ Wo,
    unsigned short* __restrict__ WF)
{
  const int plane = blockIdx.y;
  const float* __restrict__ s = (plane==0)? Wq : (plane==1)? Wk : (plane==2)? Wv : Wo;
  size_t off = ((size_t)blockIdx.x*256 + threadIdx.x) * 8;
  float4 f0 = *(const float4*)(s + off);
  float4 f1 = *(const float4*)(s + off + 4);
  *(ushort8*)&WF[(size_t)plane*1048576 + off] = pack8_rtz(f0, f1);
}

// ---------------- fused QKV projection GEMM ----------------
// z=0: Q -> f16 plane (scaled by log2e); z=1: K; z=2: V -> per-head transposed
__global__ __launch_bounds__(256) void qkv_k(
    const float* __restrict__ Aq, const float* __restrict__ Ak, const float* __restrict__ Av,
    const unsigned short* __restrict__ WF,
    const float* __restrict__ bq, const float* __restrict__ bk, const float* __restrict__ bv,
    unsigned short* __restrict__ Qf, unsigned short* __restrict__ Kf, unsigned short* __restrict__ Vt)
{
  const int z = blockIdx.z;
  const float* __restrict__ A    = (z==0)? Aq : (z==1)? Ak : Av;
  const unsigned short* __restrict__ W = WF + (size_t)z*1048576;
  const float* __restrict__ bias = (z==0)? bq : (z==1)? bk : bv;

  __shared__ unsigned short Ah[128*32];
  __shared__ unsigned short Bh[128*32];

  const int tid  = threadIdx.x;
  const int lane = tid & 63;
  const int w    = tid >> 6;
  const int wm   = w >> 1, wn = w & 1;
  const int row0 = blockIdx.x * 128;
  const int col0 = blockIdx.y * 128;

  f32x4 acc[4][4] = {};

  for (int k0 = 0; k0 < 1024; k0 += 32) {
    __syncthreads();
    #pragma unroll
    for (int j=0;j<2;++j) {
      int r  = w*32 + j*16 + (lane>>2);
      int sl = (lane & 3) ^ ((r>>1)&3);
      gload16(W + (size_t)(col0 + r)*1024 + k0 + sl*8, &Bh[(w*32 + j*16)*32]);
    }
    #pragma unroll
    for (int i = 0; i < 2; ++i) {
      int c = tid + i*256;            // 0..511 chunks of 8 elements
      int r = c >> 2, slot = c & 3;   // 128 rows x 4 slots
      int lidx = r*32 + ((slot ^ ((r >> 1) & 3))*8);
      const float* ap = A + (size_t)(row0 + r)*1024 + k0 + slot*8;
      float4 f0 = *(const float4*)ap;
      float4 f1 = *(const float4*)(ap + 4);
      *(ushort8*)&Ah[lidx] = pack8_rtz(f0, f1);
    }
    __syncthreads();

    f16x8 a_[4], b_[4];
    const int slotR = lane >> 4;
    #pragma unroll
    for (int m=0;m<4;++m) {
      int r = wm*64 + m*16 + (lane & 15);
      a_[m] = *(const f16x8*)&Ah[r*32 + ((slotR ^ ((r>>1)&3))*8)];
    }
    #pragma unroll
    for (int nn=0;nn<4;++nn) {
      int r = wn*64 + nn*16 + (lane & 15);
      b_[nn] = *(const f16x8*)&Bh[r*32 + ((slotR ^ ((r>>1)&3))*8)];
    }
    #pragma unroll
    for (int m=0;m<4;++m)
      #pragma unroll
      for (int nn=0;nn<4;++nn)
        acc[m][nn] = __builtin_amdgcn_mfma_f32_16x16x32_f16(a_[m], b_[nn], acc[m][nn],0,0,0);
  }

  // epilogue (C frag: col=lane&15, row=(lane>>4)*4+r)
  #pragma unroll
  for (int m=0;m<4;++m) {
    #pragma unroll
    for (int nn=0;nn<4;++nn) {
      int gcol = col0 + wn*64 + nn*16 + (lane & 15);
      float bsv = bias[gcol];
      if (z == 2) {
        int rbase = row0 + wm*64 + m*16 + (lane>>4)*4;
        int nIdx = rbase >> 11, s0 = rbase & 2047;
        ushort4_t pk;
        #pragma unroll
        for (int r2=0;r2<4;++r2) pk[r2] = f32_to_f16u(acc[m][nn][r2] + bsv);
        *(ushort4_t*)&Vt[((size_t)(nIdx*1024 + gcol))*2048 + s0] = pk;
      } else {
        unsigned short* __restrict__ dst = (z==0)? Qf : Kf;
        const float qsc = (z==0)? LOG2E : 1.0f;   // fold log2(e) into Q
        #pragma unroll
        for (int r2=0;r2<4;++r2) {
          int grow = row0 + wm*64 + m*16 + (lane>>4)*4 + r2;
          dst[(size_t)grow*1024 + gcol] = f32_to_f16u((acc[m][nn][r2] + bsv) * qsc);
        }
      }
    }
  }
}

// ---------------- output projection: out = AO(f16) @ WoF^T + bo (f32) ------
__global__ __launch_bounds__(256) void oproj_k(
    const unsigned short* __restrict__ AO, const unsigned short* __restrict__ W,
    const float* __restrict__ bias, float* __restrict__ out)
{
  __shared__ unsigned short Ah[128*32];
  __shared__ unsigned short Bh[128*32];

  const int tid  = threadIdx.x;
  const int lane = tid & 63;
  const int w    = tid >> 6;
  const int wm   = w >> 1, wn = w & 1;
  const int row0 = blockIdx.x * 128;
  const int col0 = blockIdx.y * 128;

  f32x4 acc[4][4] = {};

  for (int k0 = 0; k0 < 1024; k0 += 32) {
    __syncthreads();
    #pragma unroll
    for (int j=0;j<2;++j) {
      int r  = w*32 + j*16 + (lane>>2);
      int sl = (lane & 3) ^ ((r>>1)&3);
      gload16(AO + (size_t)(row0 + r)*1024 + k0 + sl*8, &Ah[(w*32 + j*16)*32]);
      gload16(W  + (size_t)(col0 + r)*1024 + k0 + sl*8, &Bh[(w*32 + j*16)*32]);
    }
    __syncthreads();

    f16x8 a_[4], b_[4];
    const int slotR = lane >> 4;
    #pragma unroll
    for (int m=0;m<4;++m) {
      int r = wm*64 + m*16 + (lane & 15);
      a_[m] = *(const f16x8*)&Ah[r*32 + ((slotR ^ ((r>>1)&3))*8)];
    }
    #pragma unroll
    for (int nn=0;nn<4;++nn) {
      int r = wn*64 + nn*16 + (lane & 15);
      b_[nn] = *(const f16x8*)&Bh[r*32 + ((slotR ^ ((r>>1)&3))*8)];
    }
    #pragma unroll
    for (int m=0;m<4;++m)
      #pragma unroll
      for (int nn=0;nn<4;++nn)
        acc[m][nn] = __builtin_amdgcn_mfma_f32_16x16x32_f16(a_[m], b_[nn], acc[m][nn],0,0,0);
  }

  #pragma unroll
  for (int m=0;m<4;++m)
    #pragma unroll
    for (int nn=0;nn<4;++nn) {
      int gcol = col0 + wn*64 + nn*16 + (lane & 15);
      float bsv = bias[gcol];
      #pragma unroll
      for (int r2=0;r2<4;++r2) {
        int grow = row0 + wm*64 + m*16 + (lane>>4)*4 + r2;
        out[(size_t)grow*1024 + gcol] = acc[m][nn][r2] + bsv;
      }
    }
}

// ---------------- Flash attention: 32x32 MFMA, register-P via permlane -----
// grid 1024 blocks (16 q-tiles of 128 x 64 heads), XCD-swizzled. 32 KB LDS.
// 4 waves x 32 q-rows (q = lane&31, h = lane>>5). KVBLK=64, K/V dbuf,
// reg-staged prefetch, 1 barrier/iter.
// S^T = mfma_32x32x16(K,Q): col=q, row k = (r&3)+8*(r>>2)+4h. Softmax is one
// 32-wide lane-local pass; slow path pairs lane<->lane^32 (1 shuffle).
// P fragment for PV built IN REGISTERS: per 16-k slice, 4 cvt_pkrtz +
// 2 v_permlane32_swap_b32 (B-frag value (q,h,j) = owner (q,j>>2) reg
// 8*s_t+4h+(j&3)). No P LDS buffer at all.
__global__ __launch_bounds__(256) void attn_k(
  const unsigned short* __restrict__ Qf, const unsigned short* __restrict__ Kf,
  const unsigned short* __restrict__ Vt, unsigned short* __restrict__ AO)
{
  __shared__ unsigned short Ks[2][64*64];   // K tile (swizzled)   16 KB
  __shared__ unsigned short Vs[2][64*64];   // V^T tile (swizzled) 16 KB

  const int tid = threadIdx.x, lane = tid & 63, w = tid >> 6;
  const int q = lane & 31, h = lane >> 5;

  // T1 XCD swizzle (bijective: 1024 % 8 == 0)
  const int bid = blockIdx.x;
  const int swz = (bid & 7) * 128 + (bid >> 3);
  const int qt = swz & 15, nh = swz >> 4;
  const int n = nh >> 4, hh = nh & 15;

  // Q fragments (pre-scaled by log2e): qf[t] = Q[qrow][d = 16t + 8h + j]
  f16x8 qf[4];
  {
    int qrow = n*SEQ + qt*128 + w*32 + q;
    #pragma unroll
    for (int t=0;t<4;++t)
      qf[t] = *(const f16x8*)&Qf[(size_t)qrow*1024 + hh*64 + t*16 + h*8];
  }

  f32x16 o[2] = {};          // o[do][r] = O[d = do*32+(r&3)+8*(r>>2)+4h][q]
  float mrun = -1e30f, lrun = 0.f;   // lrun lane-partial (pair-reduced at end)

  const size_t kbase = (size_t)(n*SEQ)*1024 + hh*64;   // K plane [s][1024]
  const size_t vbase = ((size_t)(n*1024 + hh*64))*SEQ; // Vt [d][s]

  // prologue: stage K/V tile 0 (64 x 64, 8-slot XOR swizzle)
  #pragma unroll
  for (int i=0;i<2;++i){
    int c = tid + i*256; int r = c>>3, sl = c&7;
    int lidx = r*64 + ((sl^(r&7))*8);
    *(ushort8*)&Ks[0][lidx] = *(const ushort8*)&Kf[kbase + (size_t)r*1024 + sl*8];
    *(ushort8*)&Vs[0][lidx] = *(const ushort8*)&Vt[vbase + (size_t)r*SEQ + sl*8];
  }
  __syncthreads();

  int cur = 0;
  for (int kt = 0; kt < 32; ++kt) {
    // ---- prefetch next K/V tile to regs (hides under this iteration) ----
    ushort8 kreg[2], vreg[2];
    if (kt < 31) {
      #pragma unroll
      for (int i=0;i<2;++i){
        int c = tid + i*256; int r = c>>3, sl = c&7;
        kreg[i] = *(const ushort8*)&Kf[kbase + (size_t)((kt+1)*64 + r)*1024 + sl*8];
        vreg[i] = *(const ushort8*)&Vt[vbase + (size_t)r*SEQ + (kt+1)*64 + sl*8];
      }
    }

    // ---- S^T = K * Q^T : two 32x32 tiles (st), contraction d via 4 MFMAs --
    f32x16 s[2] = {};
    __builtin_amdgcn_s_setprio(1);
    #pragma unroll
    for (int t=0; t<4; ++t) {
      int gr = ((2*t+h) ^ (q&7))*8;             // row&7 == q&7 for both st
      f16x8 k0 = *(const f16x8*)&Ks[cur][(q     )*64 + gr];
      f16x8 k1 = *(const f16x8*)&Ks[cur][(32 + q)*64 + gr];
      s[0] = __builtin_amdgcn_mfma_f32_32x32x16_f16(k0, qf[t], s[0],0,0,0);
      s[1] = __builtin_amdgcn_mfma_f32_32x32x16_f16(k1, qf[t], s[1],0,0,0);
    }
    __builtin_amdgcn_s_setprio(0);

    // ---- softmax: single 32-wide lane-local pass (defer-max T13) ----
    float m01 = fmaxf(fmaxf(s[0][0], s[0][1]), fmaxf(s[0][2], s[0][3]));
    float m02 = fmaxf(fmaxf(s[0][4], s[0][5]), fmaxf(s[0][6], s[0][7]));
    float m03 = fmaxf(fmaxf(s[0][8], s[0][9]), fmaxf(s[0][10], s[0][11]));
    float m04 = fmaxf(fmaxf(s[0][12], s[0][13]), fmaxf(s[0][14], s[0][15]));
    float m11 = fmaxf(fmaxf(s[1][0], s[1][1]), fmaxf(s[1][2], s[1][3]));
    float m12 = fmaxf(fmaxf(s[1][4], s[1][5]), fmaxf(s[1][6], s[1][7]));
    float m13 = fmaxf(fmaxf(s[1][8], s[1][9]), fmaxf(s[1][10], s[1][11]));
    float m14 = fmaxf(fmaxf(s[1][12], s[1][13]), fmaxf(s[1][14], s[1][15]));
    float ml = fmaxf(fmaxf(fmaxf(m01,m02), fmaxf(m03,m04)),
                     fmaxf(fmaxf(m11,m12), fmaxf(m13,m14)));
    if (!__all(ml <= mrun + 7.0f)) {
      // slow path: pair max (lane ^ 32), rescale O and lane-partial lsum
      float m2 = fmaxf(ml, __shfl_xor(ml, 32, 64));
      float mn = fmaxf(mrun, m2);
      float sc = __builtin_amdgcn_exp2f(mrun - mn);
      lrun *= sc;
      mrun = mn;
      #pragma unroll
      for (int dd=0; dd<2; ++dd)
        #pragma unroll
        for (int r=0;r<16;++r) o[dd][r] *= sc;
    }
    {
      float m0 = mrun;
      float rsl = 0.f;
      #pragma unroll
      for (int st=0; st<2; ++st)
        #pragma unroll
        for (int r=0;r<16;++r) {
          float p = __builtin_amdgcn_exp2f(s[st][r] - m0);
          s[st][r] = p; rsl += p;
        }
      lrun += rsl;
    }

    // ---- P fragments in registers: cvt_pk + permlane32_swap ----
    // pf[2*st+s_t] = B-frag (n=q, k=8h+j) for 16-k slice
    f16x8 pf[4];
    #pragma unroll
    for (int st=0; st<2; ++st)
      #pragma unroll
      for (int s_t=0; s_t<2; ++s_t) {
        unsigned int a0 = pk_u32(s[st][8*s_t+0], s[st][8*s_t+1]);
        unsigned int a1 = pk_u32(s[st][8*s_t+2], s[st][8*s_t+3]);
        unsigned int b0 = pk_u32(s[st][8*s_t+4], s[st][8*s_t+5]);
        unsigned int b1 = pk_u32(s[st][8*s_t+6], s[st][8*s_t+7]);
        asm("v_permlane32_swap_b32 %0, %1" : "+v"(a0), "+v"(b0));
        asm("v_permlane32_swap_b32 %0, %1" : "+v"(a1), "+v"(b1));
        union { unsigned int u[4]; f16x8 v; } pkk;
        pkk.u[0] = a0; pkk.u[1] = a1; pkk.u[2] = b0; pkk.u[3] = b1;
        pf[st*2 + s_t] = pkk.v;
      }

    // ---- O^T += V^T * P : A = V^T frag (LDS), B = pf (registers) ----
    #pragma unroll
    for (int sg=0; sg<4; ++sg) {
      int gr = ((2*sg+h) ^ (q&7))*8;            // row&7 == q&7 for both do
      f16x8 v0 = *(const f16x8*)&Vs[cur][(q     )*64 + gr];
      f16x8 v1 = *(const f16x8*)&Vs[cur][(32 + q)*64 + gr];
      __builtin_amdgcn_s_setprio(1);
      o[0] = __builtin_amdgcn_mfma_f32_32x32x16_f16(v0, pf[sg], o[0],0,0,0);
      o[1] = __builtin_amdgcn_mfma_f32_32x32x16_f16(v1, pf[sg], o[1],0,0,0);
      __builtin_amdgcn_s_setprio(0);
    }

    // ---- write staged tiles to the other buffer; 1 barrier/iter ----
    if (kt < 31) {
      #pragma unroll
      for (int i=0;i<2;++i){
        int c = tid + i*256; int r = c>>3, sl = c&7;
        int lidx = r*64 + ((sl^(r&7))*8);
        *(ushort8*)&Ks[cur^1][lidx] = kreg[i];
        *(ushort8*)&Vs[cur^1][lidx] = vreg[i];
      }
    }
    __syncthreads();
    cur ^= 1;
  }

  // epilogue: pair lsum reduce (lane ^ 32), packed 8B stores
  float rs = lrun + __shfl_xor(lrun, 32, 64);
  float inv = 1.0f / rs;
  int qrow = n*SEQ + qt*128 + w*32 + q;
  #pragma unroll
  for (int dd=0; dd<2; ++dd)
    #pragma unroll
    for (int rq=0; rq<4; ++rq) {
      union { fp16x2_t h2[2]; ushort4_t u4; } pk4;
      pk4.h2[0] = __builtin_amdgcn_cvt_pkrtz(o[dd][4*rq+0]*inv, o[dd][4*rq+1]*inv);
      pk4.h2[1] = __builtin_amdgcn_cvt_pkrtz(o[dd][4*rq+2]*inv, o[dd][4*rq+3]*inv);
      int d0 = dd*32 + 8*rq + 4*h;
      *(ushort4_t*)&AO[(size_t)qrow*1024 + hh*64 + d0] = pk4.u4;
    }
}

extern "C" void kernel_launch(void* const* d_in, const int* in_sizes, int n_in,
                              void* d_out, int out_size, void* d_ws, size_t ws_size,
                              hipStream_t stream)
{
  (void)in_sizes; (void)n_in; (void)out_size; (void)ws_size;
  const float* query = (const float*)d_in[0];
  const float* key   = (const float*)d_in[1];
  const float* value = (const float*)d_in[2];
  const float* Wq = (const float*)d_in[3];
  const float* bq = (const float*)d_in[4];
  const float* Wk = (const float*)d_in[5];
  const float* bk = (const float*)d_in[6];
  const float* Wv = (const float*)d_in[7];
  const float* bv = (const float*)d_in[8];
  const float* Wo = (const float*)d_in[9];
  const float* bo = (const float*)d_in[10];
  float* out = (float*)d_out;

  unsigned short* ws = (unsigned short*)d_ws;
  const size_t PLANE = (size_t)MROWS * 1024;
  unsigned short* Qf = ws;
  unsigned short* Kf = Qf + PLANE;
  unsigned short* Vt = Kf + PLANE;   // [ (n*16+h)*64+d ][ s ]
  unsigned short* AO = Vt + PLANE;
  unsigned short* WF = AO + PLANE;   // 4 x 1024x1024 f16 weight planes

  dim3 bb(256);
  wconv_k<<<dim3(512,4), bb, 0, stream>>>(Wq, Wk, Wv, Wo, WF);
  qkv_k <<<dim3(64,8,3), bb, 0, stream>>>(query,key,value, WF, bq,bk,bv, Qf,Kf,Vt);
  attn_k<<<dim3(1024), bb, 0, stream>>>(Qf, Kf, Vt, AO);
  oproj_k<<<dim3(64,8), bb, 0, stream>>>(AO, WF + 3*1048576, bo, out);
}